// Round 7
// baseline (320.780 us; speedup 1.0000x reference)
//
#include <hip/hip_runtime.h>

// GIN layer: agg = segment_sum(x[col], row); h = (1+eps)*x + agg;
// h = h@W1.T + b1; BN(train); ReLU; out = h@W2.T + b2
// N=100000, E=1600000, F=128. Inputs fp32; internal bf16 + MFMA.

#define F 128
#define NPB 32          // nodes per bucket
#define CLCAP 1536      // LDS clist capacity per bucket (avg cnt ~512)
#define PB 64           // partition blocks for hist/scatter (must match!)

typedef __attribute__((ext_vector_type(8))) short short8;
typedef __attribute__((ext_vector_type(4))) float float4v;

__device__ inline float b2f(unsigned short u) {
    union { unsigned int i; float f; } v; v.i = ((unsigned int)u) << 16; return v.f;
}
__device__ inline unsigned short f2b(float f) {
    union { float f; unsigned int i; } v; v.f = f;
    unsigned int r = v.i + 0x7FFFu + ((v.i >> 16) & 1u);
    return (unsigned short)(r >> 16);
}

// ---------- K0: convert x -> bf16, W1,W2 -> bf16, zero stats (fused) ----------
__global__ __launch_bounds__(256) void conv_kernel(const float* __restrict__ x,
                                                   unsigned short* __restrict__ xh, int total,
                                                   const float* __restrict__ W1,
                                                   const float* __restrict__ W2,
                                                   unsigned short* __restrict__ w1h,
                                                   unsigned short* __restrict__ w2h,
                                                   float* __restrict__ stats) {
    int t = blockIdx.x * 256 + threadIdx.x;
    int i = t * 8;
    if (i < total) {
        float4 v0 = *(const float4*)(x + i);
        float4 v1 = *(const float4*)(x + i + 4);
        short8 o;
        o[0] = (short)f2b(v0.x); o[1] = (short)f2b(v0.y); o[2] = (short)f2b(v0.z); o[3] = (short)f2b(v0.w);
        o[4] = (short)f2b(v1.x); o[5] = (short)f2b(v1.y); o[6] = (short)f2b(v1.z); o[7] = (short)f2b(v1.w);
        *(short8*)(xh + i) = o;
    }
    if (t < F * F) {
        w1h[t] = f2b(W1[t]);
        w2h[t] = f2b(W2[t]);
    }
    if (blockIdx.x == 0 && threadIdx.x < 256) stats[threadIdx.x] = 0.f;
}

// ---------- K1: per-partition bucket histogram -> hist2d[j][b] (no global atomics) ----------
__global__ __launch_bounds__(1024) void part_hist_kernel(const int* __restrict__ rows,
                                                         int* __restrict__ hist2d,
                                                         int E, int nbuk) {
    extern __shared__ int bh[];
    int tid = threadIdx.x;
    for (int i = tid; i < nbuk; i += 1024) bh[i] = 0;
    __syncthreads();
    int chunk = (E + gridDim.x - 1) / gridDim.x;
    int e0 = blockIdx.x * chunk;
    int e1 = min(E, e0 + chunk);
    for (int i = e0 + tid; i < e1; i += 1024)
        atomicAdd(&bh[rows[i] >> 5], 1);
    __syncthreads();
    int* out = hist2d + (size_t)blockIdx.x * nbuk;
    for (int b = tid; b < nbuk; b += 1024) out[b] = bh[b];
}

// ---------- K1b: per-bucket exclusive scan over partitions (in-place) + totals ----------
// Block: 256 threads = 4 groups x 64 buckets; group g scans j in [g*PB/4,(g+1)*PB/4).
__global__ __launch_bounds__(256) void colscan_kernel(int* __restrict__ hist2d,
                                                      int* __restrict__ bucketCnt, int nbuk) {
    __shared__ int gs[4][64];
    const int JG = PB / 4;
    int lb = threadIdx.x & 63, g = threadIdx.x >> 6;
    int b = blockIdx.x * 64 + lb;
    int s = 0;
    if (b < nbuk)
        for (int j = g * JG; j < (g + 1) * JG; j++) s += hist2d[(size_t)j * nbuk + b];
    gs[g][lb] = s;
    __syncthreads();
    int base = 0;
    for (int gg = 0; gg < g; gg++) base += gs[gg][lb];
    if (g == 0 && b < nbuk)
        bucketCnt[b] = gs[0][lb] + gs[1][lb] + gs[2][lb] + gs[3][lb];
    if (b < nbuk) {
        int run = base;
        for (int j = g * JG; j < (g + 1) * JG; j++) {
            size_t idx = (size_t)j * nbuk + b;
            int v = hist2d[idx];
            hist2d[idx] = run;
            run += v;
        }
    }
}

// ---------- K2: exclusive scan of bucket counts ----------
__global__ void scan_buckets_kernel(const int* __restrict__ bucketCnt, int* __restrict__ bOffs,
                                    int nbuk) {
    const int SEG = 13;   // 256*13 = 3328 >= nbuk(3125)
    __shared__ int tmp[256];
    int t = threadIdx.x;
    int base = t * SEG;
    int v[SEG], s = 0;
#pragma unroll
    for (int j = 0; j < SEG; j++) {
        int idx = base + j;
        v[j] = (idx < nbuk) ? bucketCnt[idx] : 0;
        s += v[j];
    }
    tmp[t] = s;
    __syncthreads();
    for (int off = 1; off < 256; off <<= 1) {
        int u = (t >= off) ? tmp[t - off] : 0;
        __syncthreads();
        tmp[t] += u;
        __syncthreads();
    }
    int run = tmp[t] - s;
#pragma unroll
    for (int j = 0; j < SEG; j++) {
        int idx = base + j;
        if (idx < nbuk) bOffs[idx] = run;
        run += v[j];
    }
    if (t == 255) bOffs[nbuk] = tmp[255];
}

// ---------- K3: scatter using precomputed per-(partition,bucket) bases (no global atomics) ----------
__global__ __launch_bounds__(1024) void part_scatter_kernel(const int* __restrict__ rows,
                                                            const int* __restrict__ cols,
                                                            const int* __restrict__ hist2d,
                                                            const int* __restrict__ bOffs,
                                                            int* __restrict__ recbuf,
                                                            int E, int nbuk) {
    extern __shared__ int sm[];
    int* gb = sm;
    int* bh = sm + nbuk;
    int tid = threadIdx.x;
    const int* pre = hist2d + (size_t)blockIdx.x * nbuk;
    for (int b = tid; b < nbuk; b += 1024) {
        gb[b] = bOffs[b] + pre[b];
        bh[b] = 0;
    }
    __syncthreads();
    int chunk = (E + gridDim.x - 1) / gridDim.x;
    int e0 = blockIdx.x * chunk;
    int e1 = min(E, e0 + chunk);
    for (int i = e0 + tid; i < e1; i += 1024) {
        int r = rows[i], c = cols[i];
        int k = r >> 5;
        int rk = atomicAdd(&bh[k], 1);
        recbuf[gb[k] + rk] = (c << 5) | (r & 31);
    }
}

// ---------- K4: fused per-bucket counting sort + gather-aggregate ----------
// Block = one bucket of 32 nodes, 256 threads. Sort bucket's edges by node into
// LDS clist (global fallback if cnt > CLCAP), then 4 waves each aggregate 8
// nodes: 16 lanes per row (short8=16B/lane), 4-way edge interleave, batched
// predicated tail. h0h = bf16((1+eps)*x + sum_nb x).
__global__ __launch_bounds__(256) void sort_agg_kernel(const int* __restrict__ recbuf,
                                                       const int* __restrict__ bOffs,
                                                       const unsigned short* __restrict__ xh,
                                                       const float* __restrict__ epsPtr,
                                                       unsigned short* __restrict__ h0h,
                                                       int* __restrict__ clist,
                                                       int n, int nbuk) {
    __shared__ int hist[NPB];
    __shared__ int cur[NPB];
    __shared__ int offs_s[NPB + 1];
    __shared__ int cl[CLCAP];
    int b = blockIdx.x, tid = threadIdx.x;
    int base = bOffs[b];
    int cnt = bOffs[b + 1] - base;
    if (tid < NPB) hist[tid] = 0;
    __syncthreads();
    for (int i = tid; i < cnt; i += 256) atomicAdd(&hist[recbuf[base + i] & (NPB - 1)], 1);
    __syncthreads();
    if (tid < NPB) {
        int h = hist[tid], v = h;
#pragma unroll
        for (int off = 1; off < NPB; off <<= 1) {
            int u = __shfl_up(v, off, 64);
            if (tid >= off) v += u;
        }
        cur[tid] = v - h;
        offs_s[tid] = v - h;
        if (tid == NPB - 1) offs_s[NPB] = v;
    }
    __syncthreads();
    bool inlds = (cnt <= CLCAP);
    if (inlds) {
        for (int i = tid; i < cnt; i += 256) {
            int r = recbuf[base + i];
            int p = atomicAdd(&cur[r & (NPB - 1)], 1);
            cl[p] = r >> 5;
        }
    } else {
        for (int i = tid; i < cnt; i += 256) {
            int r = recbuf[base + i];
            int p = atomicAdd(&cur[r & (NPB - 1)], 1);
            clist[base + p] = r >> 5;
        }
    }
    __syncthreads();

    // aggregate: wave wv handles nodes wv, wv+4, ..., of this bucket
    int wv = tid >> 6, lane = tid & 63;
    int qt = lane >> 4;          // which edge within group of 4
    int c16 = lane & 15;         // channel chunk: channels 8*c16 .. 8*c16+7
    const short8* xh8 = (const short8*)xh;
    float sc = 1.0f + epsPtr[0];
    const int* glist = clist + base;
    for (int nd = wv; nd < NPB; nd += 4) {
        int node = b * NPB + nd;
        if (node >= n) break;
        int s = offs_s[nd], e = offs_s[nd + 1];
        float acc[8];
#pragma unroll
        for (int j = 0; j < 8; j++) acc[j] = 0.f;
        int i = s;
        for (; i + 16 <= e; i += 16) {
            int c[4];
#pragma unroll
            for (int u = 0; u < 4; u++) {
                int idx = i + 4 * u + qt;
                c[u] = inlds ? cl[idx] : glist[idx];
            }
            short8 v[4];
#pragma unroll
            for (int u = 0; u < 4; u++) v[u] = xh8[(size_t)c[u] * 16 + c16];
#pragma unroll
            for (int u = 0; u < 4; u++)
#pragma unroll
                for (int j = 0; j < 8; j++) acc[j] += b2f((unsigned short)v[u][j]);
        }
        if (i < e) {
            int c[4];
#pragma unroll
            for (int u = 0; u < 4; u++) {
                int idx = i + 4 * u + qt;
                c[u] = (idx < e) ? (inlds ? cl[idx] : glist[idx]) : -1;
            }
            short8 v[4];
#pragma unroll
            for (int u = 0; u < 4; u++)
                v[u] = xh8[(size_t)(c[u] < 0 ? 0 : c[u]) * 16 + c16];
#pragma unroll
            for (int u = 0; u < 4; u++) {
                if (c[u] >= 0) {
#pragma unroll
                    for (int j = 0; j < 8; j++) acc[j] += b2f((unsigned short)v[u][j]);
                }
            }
        }
#pragma unroll
        for (int j = 0; j < 8; j++) {
            acc[j] += __shfl_xor(acc[j], 16, 64);
            acc[j] += __shfl_xor(acc[j], 32, 64);
        }
        if (qt == 0) {
            short8 xv = xh8[(size_t)node * 16 + c16];
            short8 o;
#pragma unroll
            for (int j = 0; j < 8; j++) {
                float r = fmaf(sc, b2f((unsigned short)xv[j]), acc[j]);
                o[j] = (short)f2b(r);
            }
            ((short8*)h0h)[(size_t)node * 16 + c16] = o;
        }
    }
}

// ---------- K5: MFMA GEMM1: h1 = h0h @ W1^T + b1 (bf16 in, fp32 acc) + BN stats ----------
#define WLD 136   // padded LDS row stride (elements)
__global__ __launch_bounds__(256, 2) void gemm1_mfma_kernel(const unsigned short* __restrict__ h0h,
                                                            const unsigned short* __restrict__ w1h,
                                                            const float* __restrict__ b1,
                                                            unsigned short* __restrict__ h1h,
                                                            float* __restrict__ stats, int n) {
    __shared__ unsigned short wl[128 * WLD];
    __shared__ float red[4 * 256];
    int tid = threadIdx.x;
    for (int i = tid; i < 128 * 16; i += 256) {
        int r = i >> 4, ch = i & 15;
        *(short8*)(wl + r * WLD + ch * 8) = *(const short8*)(w1h + r * 128 + ch * 8);
    }
    __syncthreads();

    int wv = tid >> 6, lane = tid & 63;
    int q = lane >> 4, c15 = lane & 15;
    int rowbase = blockIdx.x * 64 + wv * 16;
    int arow = rowbase + c15; if (arow >= n) arow = n - 1;
    const unsigned short* aptr = h0h + (size_t)arow * 128 + q * 8;

    float4v acc[8];
#pragma unroll
    for (int nt = 0; nt < 8; nt++) {
        float bb = b1[nt * 16 + c15];
        acc[nt] = (float4v){bb, bb, bb, bb};
    }
#pragma unroll
    for (int ks = 0; ks < 4; ks++) {
        short8 a = *(const short8*)(aptr + ks * 32);
        const unsigned short* wp = wl + q * 8 + ks * 32;
#pragma unroll
        for (int nt = 0; nt < 8; nt++) {
            short8 b = *(const short8*)(wp + (nt * 16 + c15) * WLD);
            acc[nt] = __builtin_amdgcn_mfma_f32_16x16x32_bf16(a, b, acc[nt], 0, 0, 0);
        }
    }

    float sum[8], sq[8];
#pragma unroll
    for (int nt = 0; nt < 8; nt++) {
        sum[nt] = 0.f; sq[nt] = 0.f;
#pragma unroll
        for (int r = 0; r < 4; r++) {
            int row = rowbase + q * 4 + r;
            if (row < n) {
                float v = acc[nt][r];
                h1h[(size_t)row * 128 + nt * 16 + c15] = f2b(v);
                sum[nt] += v; sq[nt] += v * v;
            }
        }
        sum[nt] += __shfl_xor(sum[nt], 16, 64);
        sum[nt] += __shfl_xor(sum[nt], 32, 64);
        sq[nt]  += __shfl_xor(sq[nt], 16, 64);
        sq[nt]  += __shfl_xor(sq[nt], 32, 64);
    }
    if (lane < 16) {
#pragma unroll
        for (int nt = 0; nt < 8; nt++) {
            red[wv * 256 + nt * 16 + c15] = sum[nt];
            red[wv * 256 + 128 + nt * 16 + c15] = sq[nt];
        }
    }
    __syncthreads();
    if (wv == 0) {
        for (int c = lane; c < 128; c += 64) {
            float S = red[c] + red[256 + c] + red[512 + c] + red[768 + c];
            float Q = red[128 + c] + red[384 + c] + red[640 + c] + red[896 + c];
            atomicAdd(&stats[c], S);
            atomicAdd(&stats[128 + c], Q);
        }
    }
}

// ---------- K7: MFMA GEMM2: out = relu(BN(h1h)) @ W2^T + b2, fp32 out ----------
// BN finalize fused into prologue: each block derives scale/shift from stats.
__global__ __launch_bounds__(256, 2) void gemm2_mfma_kernel(const unsigned short* __restrict__ h1h,
                                                            const unsigned short* __restrict__ w2h,
                                                            const float* __restrict__ b2,
                                                            const float* __restrict__ stats,
                                                            const float* __restrict__ gamma,
                                                            const float* __restrict__ beta,
                                                            float* __restrict__ out, int n) {
    __shared__ unsigned short wl[128 * WLD];
    __shared__ float ssl[256];
    int tid = threadIdx.x;
    for (int i = tid; i < 128 * 16; i += 256) {
        int r = i >> 4, ch = i & 15;
        *(short8*)(wl + r * WLD + ch * 8) = *(const short8*)(w2h + r * 128 + ch * 8);
    }
    if (tid < 128) {
        float inv_n = 1.0f / (float)n;
        float mu = stats[tid] * inv_n;
        float var = stats[F + tid] * inv_n - mu * mu;
        var = fmaxf(var, 0.0f);
        float rs = rsqrtf(var + 1e-5f);
        float s = gamma[tid] * rs;
        ssl[tid] = s;
        ssl[F + tid] = beta[tid] - mu * s;
    }
    __syncthreads();

    int wv = tid >> 6, lane = tid & 63;
    int q = lane >> 4, c15 = lane & 15;
    int rowbase = blockIdx.x * 64 + wv * 16;
    int arow = rowbase + c15; if (arow >= n) arow = n - 1;
    const unsigned short* aptr = h1h + (size_t)arow * 128 + q * 8;

    float4v acc[8];
#pragma unroll
    for (int nt = 0; nt < 8; nt++) {
        float bb = b2[nt * 16 + c15];
        acc[nt] = (float4v){bb, bb, bb, bb};
    }
#pragma unroll
    for (int ks = 0; ks < 4; ks++) {
        short8 araw = *(const short8*)(aptr + ks * 32);
        const float* ssp = ssl + ks * 32 + q * 8;
        float4 s0 = *(const float4*)(ssp);
        float4 s1 = *(const float4*)(ssp + 4);
        float4 t0 = *(const float4*)(ssp + 128);
        float4 t1 = *(const float4*)(ssp + 132);
        short8 a;
        a[0] = (short)f2b(fmaxf(fmaf(b2f((unsigned short)araw[0]), s0.x, t0.x), 0.f));
        a[1] = (short)f2b(fmaxf(fmaf(b2f((unsigned short)araw[1]), s0.y, t0.y), 0.f));
        a[2] = (short)f2b(fmaxf(fmaf(b2f((unsigned short)araw[2]), s0.z, t0.z), 0.f));
        a[3] = (short)f2b(fmaxf(fmaf(b2f((unsigned short)araw[3]), s0.w, t0.w), 0.f));
        a[4] = (short)f2b(fmaxf(fmaf(b2f((unsigned short)araw[4]), s1.x, t1.x), 0.f));
        a[5] = (short)f2b(fmaxf(fmaf(b2f((unsigned short)araw[5]), s1.y, t1.y), 0.f));
        a[6] = (short)f2b(fmaxf(fmaf(b2f((unsigned short)araw[6]), s1.z, t1.z), 0.f));
        a[7] = (short)f2b(fmaxf(fmaf(b2f((unsigned short)araw[7]), s1.w, t1.w), 0.f));
        const unsigned short* wp = wl + q * 8 + ks * 32;
#pragma unroll
        for (int nt = 0; nt < 8; nt++) {
            short8 b = *(const short8*)(wp + (nt * 16 + c15) * WLD);
            acc[nt] = __builtin_amdgcn_mfma_f32_16x16x32_bf16(a, b, acc[nt], 0, 0, 0);
        }
    }
#pragma unroll
    for (int nt = 0; nt < 8; nt++) {
#pragma unroll
        for (int r = 0; r < 4; r++) {
            int row = rowbase + q * 4 + r;
            if (row < n)
                out[(size_t)row * 128 + nt * 16 + c15] = acc[nt][r];
        }
    }
}

extern "C" void kernel_launch(void* const* d_in, const int* in_sizes, int n_in,
                              void* d_out, int out_size, void* d_ws, size_t ws_size,
                              hipStream_t stream) {
    const float* x     = (const float*)d_in[0];
    const int*   ei    = (const int*)d_in[1];
    const float* eps   = (const float*)d_in[2];
    const float* W1    = (const float*)d_in[3];
    const float* b1    = (const float*)d_in[4];
    const float* gamma = (const float*)d_in[5];
    const float* beta  = (const float*)d_in[6];
    const float* W2    = (const float*)d_in[7];
    const float* b2    = (const float*)d_in[8];
    float* out = (float*)d_out;

    const int E = in_sizes[1] / 2;
    const int n = in_sizes[0] / F;
    const int nbuk = (n + NPB - 1) / NPB;   // 3125

    char* w = (char*)d_ws;
    auto alloc = [&](size_t bytes) -> void* {
        void* p = (void*)w;
        w += (bytes + 255) & ~(size_t)255;
        return p;
    };
    int*            bucketCnt = (int*)alloc((size_t)nbuk * 4);
    int*            bOffs     = (int*)alloc((size_t)(nbuk + 1) * 4);
    int*            hist2d    = (int*)alloc((size_t)PB * nbuk * 4);
    float*          stats     = (float*)alloc(256 * 4);
    unsigned short* w1h       = (unsigned short*)alloc(F * F * 2);
    unsigned short* w2h       = (unsigned short*)alloc(F * F * 2);
    int*            recbuf    = (int*)alloc((size_t)E * 4);
    int*            clist     = (int*)alloc((size_t)E * 4);   // fallback only
    unsigned short* xh        = (unsigned short*)alloc((size_t)n * F * 2);
    unsigned short* h0h       = (unsigned short*)alloc((size_t)n * F * 2);
    unsigned short* h1h      = (unsigned short*)alloc((size_t)n * F * 2);

    const int* rows = ei;
    const int* cols = ei + E;

    conv_kernel<<<(n * F / 8 + 255) / 256, 256, 0, stream>>>(x, xh, n * F, W1, W2, w1h, w2h, stats);
    part_hist_kernel<<<PB, 1024, nbuk * 4, stream>>>(rows, hist2d, E, nbuk);
    colscan_kernel<<<(nbuk + 63) / 64, 256, 0, stream>>>(hist2d, bucketCnt, nbuk);
    scan_buckets_kernel<<<1, 256, 0, stream>>>(bucketCnt, bOffs, nbuk);
    part_scatter_kernel<<<PB, 1024, nbuk * 8, stream>>>(rows, cols, hist2d, bOffs, recbuf, E, nbuk);
    sort_agg_kernel<<<nbuk, 256, 0, stream>>>(recbuf, bOffs, xh, eps, h0h, clist, n, nbuk);

    int ntiles = (n + 63) / 64;
    gemm1_mfma_kernel<<<ntiles, 256, 0, stream>>>(h0h, w1h, b1, h1h, stats, n);
    gemm2_mfma_kernel<<<ntiles, 256, 0, stream>>>(h1h, w2h, b2, stats, gamma, beta, out, n);
}

// Round 8
// 301.587 us; speedup vs baseline: 1.0636x; 1.0636x over previous
//
#include <hip/hip_runtime.h>

// GIN layer: agg = segment_sum(x[col], row); h = (1+eps)*x + agg;
// h = h@W1.T + b1; BN(train); ReLU; out = h@W2.T + b2
// N=100000, E=1600000, F=128. Inputs fp32; internal bf16 + MFMA.

#define F 128
#define NPB 64          // nodes per bucket

typedef __attribute__((ext_vector_type(8))) short short8;
typedef __attribute__((ext_vector_type(4))) float float4v;

__device__ inline float b2f(unsigned short u) {
    union { unsigned int i; float f; } v; v.i = ((unsigned int)u) << 16; return v.f;
}
__device__ inline unsigned short f2b(float f) {
    union { float f; unsigned int i; } v; v.f = f;
    unsigned int r = v.i + 0x7FFFu + ((v.i >> 16) & 1u);
    return (unsigned short)(r >> 16);
}

// ---------- K0: convert x -> bf16, W1,W2 -> bf16, zero bucketCnt+stats (fused) ----------
__global__ __launch_bounds__(256) void conv_kernel(const float* __restrict__ x,
                                                   unsigned short* __restrict__ xh, int total,
                                                   const float* __restrict__ W1,
                                                   const float* __restrict__ W2,
                                                   unsigned short* __restrict__ w1h,
                                                   unsigned short* __restrict__ w2h,
                                                   int* __restrict__ bucketCnt, int nbuk,
                                                   float* __restrict__ stats) {
    int t = blockIdx.x * 256 + threadIdx.x;
    int i = t * 8;
    if (i < total) {
        float4 v0 = *(const float4*)(x + i);
        float4 v1 = *(const float4*)(x + i + 4);
        short8 o;
        o[0] = (short)f2b(v0.x); o[1] = (short)f2b(v0.y); o[2] = (short)f2b(v0.z); o[3] = (short)f2b(v0.w);
        o[4] = (short)f2b(v1.x); o[5] = (short)f2b(v1.y); o[6] = (short)f2b(v1.z); o[7] = (short)f2b(v1.w);
        *(short8*)(xh + i) = o;
    }
    if (t < F * F) {
        w1h[t] = f2b(W1[t]);
        w2h[t] = f2b(W2[t]);
    }
    // fold the two memsets into this first kernel (stream order protects readers)
    if (blockIdx.x == 0) {
        for (int k = threadIdx.x; k < nbuk; k += 256) bucketCnt[k] = 0;
    } else if (blockIdx.x == 1) {
        if (threadIdx.x < 256) stats[threadIdx.x] = 0.f;
    }
}

// ---------- K1: bucket histogram (LDS-aggregated) ----------
__global__ __launch_bounds__(256) void bucket_hist_kernel(const int* __restrict__ rows,
                                                          int* __restrict__ bucketCnt,
                                                          int E, int nbuk) {
    extern __shared__ int bh[];
    int tid = threadIdx.x;
    for (int i = tid; i < nbuk; i += 256) bh[i] = 0;
    __syncthreads();
    int stride = gridDim.x * 256;
    for (int i = blockIdx.x * 256 + tid; i < E; i += stride)
        atomicAdd(&bh[rows[i] >> 6], 1);
    __syncthreads();
    for (int b = tid; b < nbuk; b += 256) {
        int c = bh[b];
        if (c) atomicAdd(&bucketCnt[b], c);
    }
}

// ---------- K2: exclusive scan of bucket counts ----------
__global__ void scan_buckets_kernel(const int* __restrict__ bucketCnt, int* __restrict__ bOffs,
                                    int* __restrict__ gcursor, int nbuk) {
    const int SEG = 7;
    __shared__ int tmp[256];
    int t = threadIdx.x;
    int base = t * SEG;
    int v[SEG], s = 0;
#pragma unroll
    for (int j = 0; j < SEG; j++) {
        int idx = base + j;
        v[j] = (idx < nbuk) ? bucketCnt[idx] : 0;
        s += v[j];
    }
    tmp[t] = s;
    __syncthreads();
    for (int off = 1; off < 256; off <<= 1) {
        int u = (t >= off) ? tmp[t - off] : 0;
        __syncthreads();
        tmp[t] += u;
        __syncthreads();
    }
    int run = tmp[t] - s;
#pragma unroll
    for (int j = 0; j < SEG; j++) {
        int idx = base + j;
        if (idx < nbuk) { bOffs[idx] = run; gcursor[idx] = run; }
        run += v[j];
    }
    if (t == 255) bOffs[nbuk] = tmp[255];
}

// ---------- K3: binned scatter ----------
__global__ __launch_bounds__(1024) void binned_scatter_kernel(const int* __restrict__ rows,
                                                              const int* __restrict__ cols,
                                                              int* __restrict__ gcursor,
                                                              int* __restrict__ recbuf,
                                                              int E, int nbuk) {
    extern __shared__ int sm[];
    int* bh = sm;
    int* gb = sm + nbuk;
    int tid = threadIdx.x;
    int chunk = (E + gridDim.x - 1) / gridDim.x;
    int e0 = blockIdx.x * chunk;
    int e1 = min(E, e0 + chunk);
    for (int i = tid; i < nbuk; i += 1024) bh[i] = 0;
    __syncthreads();
    for (int i = e0 + tid; i < e1; i += 1024)
        atomicAdd(&bh[rows[i] >> 6], 1);
    __syncthreads();
    for (int b = tid; b < nbuk; b += 1024) {
        int c = bh[b];
        gb[b] = c ? atomicAdd(&gcursor[b], c) : 0;
        bh[b] = 0;
    }
    __syncthreads();
    for (int i = e0 + tid; i < e1; i += 1024) {
        int r = rows[i], c = cols[i];
        int k = r >> 6;
        int rk = atomicAdd(&bh[k], 1);
        recbuf[gb[k] + rk] = (c << 6) | (r & 63);
    }
}

// ---------- K3b: per-bucket counting sort ----------
__global__ __launch_bounds__(256) void bucket_sort_kernel(const int* __restrict__ recbuf,
                                                          const int* __restrict__ bOffs,
                                                          int* __restrict__ clist,
                                                          int* __restrict__ offs,
                                                          int n, int nbuk) {
    __shared__ int hist[NPB];
    __shared__ int cur[NPB];
    int b = blockIdx.x, tid = threadIdx.x;
    int base = bOffs[b];
    int cnt = bOffs[b + 1] - base;
    if (tid < NPB) hist[tid] = 0;
    __syncthreads();
    for (int i = tid; i < cnt; i += 256) atomicAdd(&hist[recbuf[base + i] & 63], 1);
    __syncthreads();
    if (tid < 64) {
        int h = hist[tid], v = h;
#pragma unroll
        for (int off = 1; off < 64; off <<= 1) {
            int u = __shfl_up(v, off, 64);
            if (tid >= off) v += u;
        }
        cur[tid] = v - h;
        int g = b * NPB + tid;
        if (g < n) offs[g] = base + v - h;
    }
    if (b == 0 && tid == 0) offs[n] = bOffs[nbuk];
    __syncthreads();
    for (int i = tid; i < cnt; i += 256) {
        int r = recbuf[base + i];
        int p = atomicAdd(&cur[r & 63], 1);
        clist[base + p] = r >> 6;
    }
}

// ---------- K4: gather-aggregate in bf16: h0h = bf16((1+eps)*x + sum_nb x) ----------
// One wave per node. 16 lanes per row (short8 = 16B/lane), 4-way edge interleave.
// Split into two half-grid dispatches (base_node) for profiler visibility.
__global__ __launch_bounds__(256) void agg_kernel(const unsigned short* __restrict__ xh,
                                                  const int* __restrict__ offs,
                                                  const int* __restrict__ clist,
                                                  const float* __restrict__ epsPtr,
                                                  unsigned short* __restrict__ h0h,
                                                  int base_node, int n_end) {
    int wave = threadIdx.x >> 6, lane = threadIdx.x & 63;
    int node = base_node + blockIdx.x * 4 + wave;
    if (node >= n_end) return;
    int qt = lane >> 4;          // which edge within group of 4
    int c16 = lane & 15;         // channel chunk: channels 8*c16 .. 8*c16+7
    const short8* xh8 = (const short8*)xh;   // row r chunk c -> index r*16 + c
    float acc[8];
#pragma unroll
    for (int j = 0; j < 8; j++) acc[j] = 0.f;
    int s = offs[node], e = offs[node + 1];
    int i = s;
    for (; i + 16 <= e; i += 16) {
        int c[4];
#pragma unroll
        for (int u = 0; u < 4; u++) c[u] = clist[i + 4 * u + qt];
        short8 v[4];
#pragma unroll
        for (int u = 0; u < 4; u++) v[u] = xh8[(size_t)c[u] * 16 + c16];
#pragma unroll
        for (int u = 0; u < 4; u++)
#pragma unroll
            for (int j = 0; j < 8; j++) acc[j] += b2f((unsigned short)v[u][j]);
    }
    if (i < e) {
        int c[4];
#pragma unroll
        for (int u = 0; u < 4; u++) {
            int idx = i + 4 * u + qt;
            c[u] = (idx < e) ? clist[idx] : -1;
        }
        short8 v[4];
#pragma unroll
        for (int u = 0; u < 4; u++)
            v[u] = xh8[(size_t)(c[u] < 0 ? 0 : c[u]) * 16 + c16];
#pragma unroll
        for (int u = 0; u < 4; u++) {
            if (c[u] >= 0) {
#pragma unroll
                for (int j = 0; j < 8; j++) acc[j] += b2f((unsigned short)v[u][j]);
            }
        }
    }
    // reduce the 4 quarters: lanes {c16, c16+16, c16+32, c16+48} hold partials
#pragma unroll
    for (int j = 0; j < 8; j++) {
        acc[j] += __shfl_xor(acc[j], 16, 64);
        acc[j] += __shfl_xor(acc[j], 32, 64);
    }
    if (qt == 0) {
        float sc = 1.0f + epsPtr[0];
        short8 xv = xh8[(size_t)node * 16 + c16];
        short8 o;
#pragma unroll
        for (int j = 0; j < 8; j++) {
            float r = fmaf(sc, b2f((unsigned short)xv[j]), acc[j]);
            o[j] = (short)f2b(r);
        }
        ((short8*)h0h)[(size_t)node * 16 + c16] = o;
    }
}

// ---------- K5: MFMA GEMM1: h1 = h0h @ W1^T + b1 (bf16 in, fp32 acc) + BN stats ----------
#define WLD 136   // padded LDS row stride (elements)
__global__ __launch_bounds__(256, 2) void gemm1_mfma_kernel(const unsigned short* __restrict__ h0h,
                                                            const unsigned short* __restrict__ w1h,
                                                            const float* __restrict__ b1,
                                                            unsigned short* __restrict__ h1h,
                                                            float* __restrict__ stats, int n) {
    __shared__ unsigned short wl[128 * WLD];
    __shared__ float red[4 * 256];
    int tid = threadIdx.x;
    for (int i = tid; i < 128 * 16; i += 256) {
        int r = i >> 4, ch = i & 15;
        *(short8*)(wl + r * WLD + ch * 8) = *(const short8*)(w1h + r * 128 + ch * 8);
    }
    __syncthreads();

    int wv = tid >> 6, lane = tid & 63;
    int q = lane >> 4, c15 = lane & 15;
    int rowbase = blockIdx.x * 64 + wv * 16;
    int arow = rowbase + c15; if (arow >= n) arow = n - 1;
    const unsigned short* aptr = h0h + (size_t)arow * 128 + q * 8;

    float4v acc[8];
#pragma unroll
    for (int nt = 0; nt < 8; nt++) {
        float bb = b1[nt * 16 + c15];
        acc[nt] = (float4v){bb, bb, bb, bb};
    }
#pragma unroll
    for (int ks = 0; ks < 4; ks++) {
        short8 a = *(const short8*)(aptr + ks * 32);
        const unsigned short* wp = wl + q * 8 + ks * 32;
#pragma unroll
        for (int nt = 0; nt < 8; nt++) {
            short8 b = *(const short8*)(wp + (nt * 16 + c15) * WLD);
            acc[nt] = __builtin_amdgcn_mfma_f32_16x16x32_bf16(a, b, acc[nt], 0, 0, 0);
        }
    }

    // epilogue: store h1h (bf16) + per-col stats
    float sum[8], sq[8];
#pragma unroll
    for (int nt = 0; nt < 8; nt++) {
        sum[nt] = 0.f; sq[nt] = 0.f;
#pragma unroll
        for (int r = 0; r < 4; r++) {
            int row = rowbase + q * 4 + r;
            if (row < n) {
                float v = acc[nt][r];
                h1h[(size_t)row * 128 + nt * 16 + c15] = f2b(v);
                sum[nt] += v; sq[nt] += v * v;
            }
        }
        sum[nt] += __shfl_xor(sum[nt], 16, 64);
        sum[nt] += __shfl_xor(sum[nt], 32, 64);
        sq[nt]  += __shfl_xor(sq[nt], 16, 64);
        sq[nt]  += __shfl_xor(sq[nt], 32, 64);
    }
    if (lane < 16) {
#pragma unroll
        for (int nt = 0; nt < 8; nt++) {
            red[wv * 256 + nt * 16 + c15] = sum[nt];
            red[wv * 256 + 128 + nt * 16 + c15] = sq[nt];
        }
    }
    __syncthreads();
    if (wv == 0) {
        for (int c = lane; c < 128; c += 64) {
            float S = red[c] + red[256 + c] + red[512 + c] + red[768 + c];
            float Q = red[128 + c] + red[384 + c] + red[640 + c] + red[896 + c];
            atomicAdd(&stats[c], S);
            atomicAdd(&stats[128 + c], Q);
        }
    }
}

// ---------- K7: MFMA GEMM2: out = relu(BN(h1h)) @ W2^T + b2, fp32 out ----------
// BN finalize fused into prologue: each block derives scale/shift from stats.
__global__ __launch_bounds__(256, 2) void gemm2_mfma_kernel(const unsigned short* __restrict__ h1h,
                                                            const unsigned short* __restrict__ w2h,
                                                            const float* __restrict__ b2,
                                                            const float* __restrict__ stats,
                                                            const float* __restrict__ gamma,
                                                            const float* __restrict__ beta,
                                                            float* __restrict__ out, int n) {
    __shared__ unsigned short wl[128 * WLD];
    __shared__ float ssl[256];
    int tid = threadIdx.x;
    for (int i = tid; i < 128 * 16; i += 256) {
        int r = i >> 4, ch = i & 15;
        *(short8*)(wl + r * WLD + ch * 8) = *(const short8*)(w2h + r * 128 + ch * 8);
    }
    if (tid < 128) {
        float inv_n = 1.0f / (float)n;
        float mu = stats[tid] * inv_n;
        float var = stats[F + tid] * inv_n - mu * mu;
        var = fmaxf(var, 0.0f);
        float rs = rsqrtf(var + 1e-5f);
        float s = gamma[tid] * rs;
        ssl[tid] = s;
        ssl[F + tid] = beta[tid] - mu * s;
    }
    __syncthreads();

    int wv = tid >> 6, lane = tid & 63;
    int q = lane >> 4, c15 = lane & 15;
    int rowbase = blockIdx.x * 64 + wv * 16;
    int arow = rowbase + c15; if (arow >= n) arow = n - 1;
    const unsigned short* aptr = h1h + (size_t)arow * 128 + q * 8;

    float4v acc[8];
#pragma unroll
    for (int nt = 0; nt < 8; nt++) {
        float bb = b2[nt * 16 + c15];
        acc[nt] = (float4v){bb, bb, bb, bb};
    }
#pragma unroll
    for (int ks = 0; ks < 4; ks++) {
        short8 araw = *(const short8*)(aptr + ks * 32);
        const float* ssp = ssl + ks * 32 + q * 8;
        float4 s0 = *(const float4*)(ssp);
        float4 s1 = *(const float4*)(ssp + 4);
        float4 t0 = *(const float4*)(ssp + 128);
        float4 t1 = *(const float4*)(ssp + 132);
        short8 a;
        a[0] = (short)f2b(fmaxf(fmaf(b2f((unsigned short)araw[0]), s0.x, t0.x), 0.f));
        a[1] = (short)f2b(fmaxf(fmaf(b2f((unsigned short)araw[1]), s0.y, t0.y), 0.f));
        a[2] = (short)f2b(fmaxf(fmaf(b2f((unsigned short)araw[2]), s0.z, t0.z), 0.f));
        a[3] = (short)f2b(fmaxf(fmaf(b2f((unsigned short)araw[3]), s0.w, t0.w), 0.f));
        a[4] = (short)f2b(fmaxf(fmaf(b2f((unsigned short)araw[4]), s1.x, t1.x), 0.f));
        a[5] = (short)f2b(fmaxf(fmaf(b2f((unsigned short)araw[5]), s1.y, t1.y), 0.f));
        a[6] = (short)f2b(fmaxf(fmaf(b2f((unsigned short)araw[6]), s1.z, t1.z), 0.f));
        a[7] = (short)f2b(fmaxf(fmaf(b2f((unsigned short)araw[7]), s1.w, t1.w), 0.f));
        const unsigned short* wp = wl + q * 8 + ks * 32;
#pragma unroll
        for (int nt = 0; nt < 8; nt++) {
            short8 b = *(const short8*)(wp + (nt * 16 + c15) * WLD);
            acc[nt] = __builtin_amdgcn_mfma_f32_16x16x32_bf16(a, b, acc[nt], 0, 0, 0);
        }
    }
#pragma unroll
    for (int nt = 0; nt < 8; nt++) {
#pragma unroll
        for (int r = 0; r < 4; r++) {
            int row = rowbase + q * 4 + r;
            if (row < n)
                out[(size_t)row * 128 + nt * 16 + c15] = acc[nt][r];
        }
    }
}

extern "C" void kernel_launch(void* const* d_in, const int* in_sizes, int n_in,
                              void* d_out, int out_size, void* d_ws, size_t ws_size,
                              hipStream_t stream) {
    const float* x     = (const float*)d_in[0];
    const int*   ei    = (const int*)d_in[1];
    const float* eps   = (const float*)d_in[2];
    const float* W1    = (const float*)d_in[3];
    const float* b1    = (const float*)d_in[4];
    const float* gamma = (const float*)d_in[5];
    const float* beta  = (const float*)d_in[6];
    const float* W2    = (const float*)d_in[7];
    const float* b2    = (const float*)d_in[8];
    float* out = (float*)d_out;

    const int E = in_sizes[1] / 2;
    const int n = in_sizes[0] / F;
    const int nbuk = (n + NPB - 1) / NPB;   // 1563

    char* w = (char*)d_ws;
    auto alloc = [&](size_t bytes) -> void* {
        void* p = (void*)w;
        w += (bytes + 255) & ~(size_t)255;
        return p;
    };
    int*            bucketCnt = (int*)alloc((size_t)nbuk * 4);
    int*            bOffs     = (int*)alloc((size_t)(nbuk + 1) * 4);
    int*            gcursor   = (int*)alloc((size_t)nbuk * 4);
    int*            offs      = (int*)alloc((size_t)(n + 1) * 4);
    float*          stats     = (float*)alloc(256 * 4);
    unsigned short* w1h       = (unsigned short*)alloc(F * F * 2);
    unsigned short* w2h       = (unsigned short*)alloc(F * F * 2);
    int*            recbuf    = (int*)alloc((size_t)E * 4);
    int*            clist     = (int*)alloc((size_t)E * 4);
    unsigned short* xh        = (unsigned short*)alloc((size_t)n * F * 2);
    unsigned short* h0h       = (unsigned short*)alloc((size_t)n * F * 2);
    unsigned short* h1h       = (unsigned short*)alloc((size_t)n * F * 2);

    const int* rows = ei;
    const int* cols = ei + E;

    conv_kernel<<<(n * F / 8 + 255) / 256, 256, 0, stream>>>(x, xh, n * F, W1, W2, w1h, w2h,
                                                             bucketCnt, nbuk, stats);
    bucket_hist_kernel<<<256, 256, nbuk * 4, stream>>>(rows, bucketCnt, E, nbuk);
    scan_buckets_kernel<<<1, 256, 0, stream>>>(bucketCnt, bOffs, gcursor, nbuk);
    binned_scatter_kernel<<<128, 1024, nbuk * 8, stream>>>(rows, cols, gcursor, recbuf, E, nbuk);
    bucket_sort_kernel<<<nbuk, 256, 0, stream>>>(recbuf, bOffs, clist, offs, n, nbuk);

    int nhalf = n / 2;
    agg_kernel<<<(nhalf + 3) / 4, 256, 0, stream>>>(xh, offs, clist, eps, h0h, 0, nhalf);
    agg_kernel<<<(n - nhalf + 3) / 4, 256, 0, stream>>>(xh, offs, clist, eps, h0h, nhalf, n);

    int ntiles = (n + 63) / 64;
    gemm1_mfma_kernel<<<ntiles, 256, 0, stream>>>(h0h, w1h, b1, h1h, stats, n);
    gemm2_mfma_kernel<<<ntiles, 256, 0, stream>>>(h1h, w2h, b2, stats, gamma, beta, out, n);
}

// Round 9
// 294.586 us; speedup vs baseline: 1.0889x; 1.0238x over previous
//
#include <hip/hip_runtime.h>

// GIN layer: agg = segment_sum(x[col], row); h = (1+eps)*x + agg;
// h = h@W1.T + b1; BN(train); ReLU; out = h@W2.T + b2
// N=100000, E=1600000, F=128. Inputs fp32; internal bf16 + MFMA.

#define F 128
#define NPB 64          // nodes per bucket

typedef __attribute__((ext_vector_type(8))) short short8;
typedef __attribute__((ext_vector_type(4))) float float4v;

__device__ inline float b2f(unsigned short u) {
    union { unsigned int i; float f; } v; v.i = ((unsigned int)u) << 16; return v.f;
}
__device__ inline unsigned short f2b(float f) {
    union { float f; unsigned int i; } v; v.f = f;
    unsigned int r = v.i + 0x7FFFu + ((v.i >> 16) & 1u);
    return (unsigned short)(r >> 16);
}

// ---------- K0: convert x -> bf16, W1,W2 -> bf16, zero bucketCnt+stats (fused) ----------
__global__ __launch_bounds__(256) void conv_kernel(const float* __restrict__ x,
                                                   unsigned short* __restrict__ xh, int total,
                                                   const float* __restrict__ W1,
                                                   const float* __restrict__ W2,
                                                   unsigned short* __restrict__ w1h,
                                                   unsigned short* __restrict__ w2h,
                                                   int* __restrict__ bucketCnt, int nbuk,
                                                   float* __restrict__ stats) {
    int t = blockIdx.x * 256 + threadIdx.x;
    int i = t * 8;
    if (i < total) {
        float4 v0 = *(const float4*)(x + i);
        float4 v1 = *(const float4*)(x + i + 4);
        short8 o;
        o[0] = (short)f2b(v0.x); o[1] = (short)f2b(v0.y); o[2] = (short)f2b(v0.z); o[3] = (short)f2b(v0.w);
        o[4] = (short)f2b(v1.x); o[5] = (short)f2b(v1.y); o[6] = (short)f2b(v1.z); o[7] = (short)f2b(v1.w);
        *(short8*)(xh + i) = o;
    }
    if (t < F * F) {
        w1h[t] = f2b(W1[t]);
        w2h[t] = f2b(W2[t]);
    }
    // fold the two memsets into this first kernel (stream order protects readers)
    if (blockIdx.x == 0) {
        for (int k = threadIdx.x; k < nbuk; k += 256) bucketCnt[k] = 0;
    } else if (blockIdx.x == 1) {
        if (threadIdx.x < 256) stats[threadIdx.x] = 0.f;
    }
}

// ---------- K1: bucket histogram (LDS-aggregated) ----------
__global__ __launch_bounds__(256) void bucket_hist_kernel(const int* __restrict__ rows,
                                                          int* __restrict__ bucketCnt,
                                                          int E, int nbuk) {
    extern __shared__ int bh[];
    int tid = threadIdx.x;
    for (int i = tid; i < nbuk; i += 256) bh[i] = 0;
    __syncthreads();
    int stride = gridDim.x * 256;
    for (int i = blockIdx.x * 256 + tid; i < E; i += stride)
        atomicAdd(&bh[rows[i] >> 6], 1);
    __syncthreads();
    for (int b = tid; b < nbuk; b += 256) {
        int c = bh[b];
        if (c) atomicAdd(&bucketCnt[b], c);
    }
}

// ---------- K2: exclusive scan of bucket counts ----------
__global__ void scan_buckets_kernel(const int* __restrict__ bucketCnt, int* __restrict__ bOffs,
                                    int* __restrict__ gcursor, int nbuk) {
    const int SEG = 7;
    __shared__ int tmp[256];
    int t = threadIdx.x;
    int base = t * SEG;
    int v[SEG], s = 0;
#pragma unroll
    for (int j = 0; j < SEG; j++) {
        int idx = base + j;
        v[j] = (idx < nbuk) ? bucketCnt[idx] : 0;
        s += v[j];
    }
    tmp[t] = s;
    __syncthreads();
    for (int off = 1; off < 256; off <<= 1) {
        int u = (t >= off) ? tmp[t - off] : 0;
        __syncthreads();
        tmp[t] += u;
        __syncthreads();
    }
    int run = tmp[t] - s;
#pragma unroll
    for (int j = 0; j < SEG; j++) {
        int idx = base + j;
        if (idx < nbuk) { bOffs[idx] = run; gcursor[idx] = run; }
        run += v[j];
    }
    if (t == 255) bOffs[nbuk] = tmp[255];
}

// ---------- K3: binned scatter ----------
__global__ __launch_bounds__(1024) void binned_scatter_kernel(const int* __restrict__ rows,
                                                              const int* __restrict__ cols,
                                                              int* __restrict__ gcursor,
                                                              int* __restrict__ recbuf,
                                                              int E, int nbuk) {
    extern __shared__ int sm[];
    int* bh = sm;
    int* gb = sm + nbuk;
    int tid = threadIdx.x;
    int chunk = (E + gridDim.x - 1) / gridDim.x;
    int e0 = blockIdx.x * chunk;
    int e1 = min(E, e0 + chunk);
    for (int i = tid; i < nbuk; i += 1024) bh[i] = 0;
    __syncthreads();
    for (int i = e0 + tid; i < e1; i += 1024)
        atomicAdd(&bh[rows[i] >> 6], 1);
    __syncthreads();
    for (int b = tid; b < nbuk; b += 1024) {
        int c = bh[b];
        gb[b] = c ? atomicAdd(&gcursor[b], c) : 0;
        bh[b] = 0;
    }
    __syncthreads();
    for (int i = e0 + tid; i < e1; i += 1024) {
        int r = rows[i], c = cols[i];
        int k = r >> 6;
        int rk = atomicAdd(&bh[k], 1);
        recbuf[gb[k] + rk] = (c << 6) | (r & 63);
    }
}

// ---------- K3b: per-bucket counting sort ----------
__global__ __launch_bounds__(256) void bucket_sort_kernel(const int* __restrict__ recbuf,
                                                          const int* __restrict__ bOffs,
                                                          int* __restrict__ clist,
                                                          int* __restrict__ offs,
                                                          int n, int nbuk) {
    __shared__ int hist[NPB];
    __shared__ int cur[NPB];
    int b = blockIdx.x, tid = threadIdx.x;
    int base = bOffs[b];
    int cnt = bOffs[b + 1] - base;
    if (tid < NPB) hist[tid] = 0;
    __syncthreads();
    for (int i = tid; i < cnt; i += 256) atomicAdd(&hist[recbuf[base + i] & 63], 1);
    __syncthreads();
    if (tid < 64) {
        int h = hist[tid], v = h;
#pragma unroll
        for (int off = 1; off < 64; off <<= 1) {
            int u = __shfl_up(v, off, 64);
            if (tid >= off) v += u;
        }
        cur[tid] = v - h;
        int g = b * NPB + tid;
        if (g < n) offs[g] = base + v - h;
    }
    if (b == 0 && tid == 0) offs[n] = bOffs[nbuk];
    __syncthreads();
    for (int i = tid; i < cnt; i += 256) {
        int r = recbuf[base + i];
        int p = atomicAdd(&cur[r & 63], 1);
        clist[base + p] = r >> 6;
    }
}

// ---------- K4: gather-aggregate in bf16: h0h = bf16((1+eps)*x + sum_nb x) ----------
// One wave per node. 16 lanes per row (short8 = 16B/lane), 4-way edge interleave.
// Split into two half-grid dispatches (base_node) for profiler visibility.
__global__ __launch_bounds__(256) void agg_kernel(const unsigned short* __restrict__ xh,
                                                  const int* __restrict__ offs,
                                                  const int* __restrict__ clist,
                                                  const float* __restrict__ epsPtr,
                                                  unsigned short* __restrict__ h0h,
                                                  int base_node, int n_end) {
    int wave = threadIdx.x >> 6, lane = threadIdx.x & 63;
    int node = base_node + blockIdx.x * 4 + wave;
    if (node >= n_end) return;
    int qt = lane >> 4;          // which edge within group of 4
    int c16 = lane & 15;         // channel chunk: channels 8*c16 .. 8*c16+7
    const short8* xh8 = (const short8*)xh;   // row r chunk c -> index r*16 + c
    float acc[8];
#pragma unroll
    for (int j = 0; j < 8; j++) acc[j] = 0.f;
    int s = offs[node], e = offs[node + 1];
    int i = s;
    for (; i + 16 <= e; i += 16) {
        int c[4];
#pragma unroll
        for (int u = 0; u < 4; u++) c[u] = clist[i + 4 * u + qt];
        short8 v[4];
#pragma unroll
        for (int u = 0; u < 4; u++) v[u] = xh8[(size_t)c[u] * 16 + c16];
#pragma unroll
        for (int u = 0; u < 4; u++)
#pragma unroll
            for (int j = 0; j < 8; j++) acc[j] += b2f((unsigned short)v[u][j]);
    }
    if (i < e) {
        int c[4];
#pragma unroll
        for (int u = 0; u < 4; u++) {
            int idx = i + 4 * u + qt;
            c[u] = (idx < e) ? clist[idx] : -1;
        }
        short8 v[4];
#pragma unroll
        for (int u = 0; u < 4; u++)
            v[u] = xh8[(size_t)(c[u] < 0 ? 0 : c[u]) * 16 + c16];
#pragma unroll
        for (int u = 0; u < 4; u++) {
            if (c[u] >= 0) {
#pragma unroll
                for (int j = 0; j < 8; j++) acc[j] += b2f((unsigned short)v[u][j]);
            }
        }
    }
    // reduce the 4 quarters: lanes {c16, c16+16, c16+32, c16+48} hold partials
#pragma unroll
    for (int j = 0; j < 8; j++) {
        acc[j] += __shfl_xor(acc[j], 16, 64);
        acc[j] += __shfl_xor(acc[j], 32, 64);
    }
    if (qt == 0) {
        float sc = 1.0f + epsPtr[0];
        short8 xv = xh8[(size_t)node * 16 + c16];
        short8 o;
#pragma unroll
        for (int j = 0; j < 8; j++) {
            float r = fmaf(sc, b2f((unsigned short)xv[j]), acc[j]);
            o[j] = (short)f2b(r);
        }
        ((short8*)h0h)[(size_t)node * 16 + c16] = o;
    }
}

// ---------- K5: MFMA GEMM1: h1 = h0h @ W1^T + b1 (bf16 in, fp32 acc) + BN partials ----------
// Stats epilogue is ATOMIC-FREE: per-block partial sums -> partials[block][256].
#define WLD 136   // padded LDS row stride (elements)
__global__ __launch_bounds__(256, 2) void gemm1_mfma_kernel(const unsigned short* __restrict__ h0h,
                                                            const unsigned short* __restrict__ w1h,
                                                            const float* __restrict__ b1,
                                                            unsigned short* __restrict__ h1h,
                                                            float* __restrict__ partials, int n) {
    __shared__ unsigned short wl[128 * WLD];
    __shared__ float red[4 * 256];
    int tid = threadIdx.x;
    for (int i = tid; i < 128 * 16; i += 256) {
        int r = i >> 4, ch = i & 15;
        *(short8*)(wl + r * WLD + ch * 8) = *(const short8*)(w1h + r * 128 + ch * 8);
    }
    __syncthreads();

    int wv = tid >> 6, lane = tid & 63;
    int q = lane >> 4, c15 = lane & 15;
    int rowbase = blockIdx.x * 64 + wv * 16;
    int arow = rowbase + c15; if (arow >= n) arow = n - 1;
    const unsigned short* aptr = h0h + (size_t)arow * 128 + q * 8;

    float4v acc[8];
#pragma unroll
    for (int nt = 0; nt < 8; nt++) {
        float bb = b1[nt * 16 + c15];
        acc[nt] = (float4v){bb, bb, bb, bb};
    }
#pragma unroll
    for (int ks = 0; ks < 4; ks++) {
        short8 a = *(const short8*)(aptr + ks * 32);
        const unsigned short* wp = wl + q * 8 + ks * 32;
#pragma unroll
        for (int nt = 0; nt < 8; nt++) {
            short8 b = *(const short8*)(wp + (nt * 16 + c15) * WLD);
            acc[nt] = __builtin_amdgcn_mfma_f32_16x16x32_bf16(a, b, acc[nt], 0, 0, 0);
        }
    }

    // epilogue: store h1h (bf16) + per-col partial sums (no global atomics)
    float sum[8], sq[8];
#pragma unroll
    for (int nt = 0; nt < 8; nt++) {
        sum[nt] = 0.f; sq[nt] = 0.f;
#pragma unroll
        for (int r = 0; r < 4; r++) {
            int row = rowbase + q * 4 + r;
            if (row < n) {
                float v = acc[nt][r];
                h1h[(size_t)row * 128 + nt * 16 + c15] = f2b(v);
                sum[nt] += v; sq[nt] += v * v;
            }
        }
        sum[nt] += __shfl_xor(sum[nt], 16, 64);
        sum[nt] += __shfl_xor(sum[nt], 32, 64);
        sq[nt]  += __shfl_xor(sq[nt], 16, 64);
        sq[nt]  += __shfl_xor(sq[nt], 32, 64);
    }
    if (lane < 16) {
#pragma unroll
        for (int nt = 0; nt < 8; nt++) {
            red[wv * 256 + nt * 16 + c15] = sum[nt];
            red[wv * 256 + 128 + nt * 16 + c15] = sq[nt];
        }
    }
    __syncthreads();
    if (wv == 0) {
        float* pout = partials + (size_t)blockIdx.x * 256;
        for (int c = lane; c < 128; c += 64) {
            float S = red[c] + red[256 + c] + red[512 + c] + red[768 + c];
            float Q = red[128 + c] + red[384 + c] + red[640 + c] + red[896 + c];
            pout[c] = S;
            pout[128 + c] = Q;
        }
    }
}

// ---------- K6: reduce per-block partials -> stats (16-deep atomic chains only) ----------
__global__ __launch_bounds__(256) void bn_reduce_kernel(const float* __restrict__ partials,
                                                        float* __restrict__ stats, int nb) {
    int t = threadIdx.x;
    int per = (nb + gridDim.x - 1) / gridDim.x;
    int j0 = blockIdx.x * per, j1 = min(nb, j0 + per);
    float s = 0.f;
    for (int j = j0; j < j1; j++) s += partials[(size_t)j * 256 + t];
    atomicAdd(&stats[t], s);
}

// ---------- K7: MFMA GEMM2: out = relu(BN(h1h)) @ W2^T + b2, fp32 out ----------
// BN finalize fused into prologue: each block derives scale/shift from stats.
__global__ __launch_bounds__(256, 2) void gemm2_mfma_kernel(const unsigned short* __restrict__ h1h,
                                                            const unsigned short* __restrict__ w2h,
                                                            const float* __restrict__ b2,
                                                            const float* __restrict__ stats,
                                                            const float* __restrict__ gamma,
                                                            const float* __restrict__ beta,
                                                            float* __restrict__ out, int n) {
    __shared__ unsigned short wl[128 * WLD];
    __shared__ float ssl[256];
    int tid = threadIdx.x;
    for (int i = tid; i < 128 * 16; i += 256) {
        int r = i >> 4, ch = i & 15;
        *(short8*)(wl + r * WLD + ch * 8) = *(const short8*)(w2h + r * 128 + ch * 8);
    }
    if (tid < 128) {
        float inv_n = 1.0f / (float)n;
        float mu = stats[tid] * inv_n;
        float var = stats[F + tid] * inv_n - mu * mu;
        var = fmaxf(var, 0.0f);
        float rs = rsqrtf(var + 1e-5f);
        float s = gamma[tid] * rs;
        ssl[tid] = s;
        ssl[F + tid] = beta[tid] - mu * s;
    }
    __syncthreads();

    int wv = tid >> 6, lane = tid & 63;
    int q = lane >> 4, c15 = lane & 15;
    int rowbase = blockIdx.x * 64 + wv * 16;
    int arow = rowbase + c15; if (arow >= n) arow = n - 1;
    const unsigned short* aptr = h1h + (size_t)arow * 128 + q * 8;

    float4v acc[8];
#pragma unroll
    for (int nt = 0; nt < 8; nt++) {
        float bb = b2[nt * 16 + c15];
        acc[nt] = (float4v){bb, bb, bb, bb};
    }
#pragma unroll
    for (int ks = 0; ks < 4; ks++) {
        short8 araw = *(const short8*)(aptr + ks * 32);
        const float* ssp = ssl + ks * 32 + q * 8;
        float4 s0 = *(const float4*)(ssp);
        float4 s1 = *(const float4*)(ssp + 4);
        float4 t0 = *(const float4*)(ssp + 128);
        float4 t1 = *(const float4*)(ssp + 132);
        short8 a;
        a[0] = (short)f2b(fmaxf(fmaf(b2f((unsigned short)araw[0]), s0.x, t0.x), 0.f));
        a[1] = (short)f2b(fmaxf(fmaf(b2f((unsigned short)araw[1]), s0.y, t0.y), 0.f));
        a[2] = (short)f2b(fmaxf(fmaf(b2f((unsigned short)araw[2]), s0.z, t0.z), 0.f));
        a[3] = (short)f2b(fmaxf(fmaf(b2f((unsigned short)araw[3]), s0.w, t0.w), 0.f));
        a[4] = (short)f2b(fmaxf(fmaf(b2f((unsigned short)araw[4]), s1.x, t1.x), 0.f));
        a[5] = (short)f2b(fmaxf(fmaf(b2f((unsigned short)araw[5]), s1.y, t1.y), 0.f));
        a[6] = (short)f2b(fmaxf(fmaf(b2f((unsigned short)araw[6]), s1.z, t1.z), 0.f));
        a[7] = (short)f2b(fmaxf(fmaf(b2f((unsigned short)araw[7]), s1.w, t1.w), 0.f));
        const unsigned short* wp = wl + q * 8 + ks * 32;
#pragma unroll
        for (int nt = 0; nt < 8; nt++) {
            short8 b = *(const short8*)(wp + (nt * 16 + c15) * WLD);
            acc[nt] = __builtin_amdgcn_mfma_f32_16x16x32_bf16(a, b, acc[nt], 0, 0, 0);
        }
    }
#pragma unroll
    for (int nt = 0; nt < 8; nt++) {
#pragma unroll
        for (int r = 0; r < 4; r++) {
            int row = rowbase + q * 4 + r;
            if (row < n)
                out[(size_t)row * 128 + nt * 16 + c15] = acc[nt][r];
        }
    }
}

extern "C" void kernel_launch(void* const* d_in, const int* in_sizes, int n_in,
                              void* d_out, int out_size, void* d_ws, size_t ws_size,
                              hipStream_t stream) {
    const float* x     = (const float*)d_in[0];
    const int*   ei    = (const int*)d_in[1];
    const float* eps   = (const float*)d_in[2];
    const float* W1    = (const float*)d_in[3];
    const float* b1    = (const float*)d_in[4];
    const float* gamma = (const float*)d_in[5];
    const float* beta  = (const float*)d_in[6];
    const float* W2    = (const float*)d_in[7];
    const float* b2    = (const float*)d_in[8];
    float* out = (float*)d_out;

    const int E = in_sizes[1] / 2;
    const int n = in_sizes[0] / F;
    const int nbuk = (n + NPB - 1) / NPB;   // 1563
    const int ntiles = (n + 63) / 64;       // 1563

    char* w = (char*)d_ws;
    auto alloc = [&](size_t bytes) -> void* {
        void* p = (void*)w;
        w += (bytes + 255) & ~(size_t)255;
        return p;
    };
    int*            bucketCnt = (int*)alloc((size_t)nbuk * 4);
    int*            bOffs     = (int*)alloc((size_t)(nbuk + 1) * 4);
    int*            gcursor   = (int*)alloc((size_t)nbuk * 4);
    int*            offs      = (int*)alloc((size_t)(n + 1) * 4);
    float*          stats     = (float*)alloc(256 * 4);
    float*          partials  = (float*)alloc((size_t)ntiles * 256 * 4);
    unsigned short* w1h       = (unsigned short*)alloc(F * F * 2);
    unsigned short* w2h       = (unsigned short*)alloc(F * F * 2);
    int*            recbuf    = (int*)alloc((size_t)E * 4);
    int*            clist     = (int*)alloc((size_t)E * 4);
    unsigned short* xh        = (unsigned short*)alloc((size_t)n * F * 2);
    unsigned short* h0h       = (unsigned short*)alloc((size_t)n * F * 2);
    unsigned short* h1h       = (unsigned short*)alloc((size_t)n * F * 2);

    const int* rows = ei;
    const int* cols = ei + E;

    conv_kernel<<<(n * F / 8 + 255) / 256, 256, 0, stream>>>(x, xh, n * F, W1, W2, w1h, w2h,
                                                             bucketCnt, nbuk, stats);
    bucket_hist_kernel<<<256, 256, nbuk * 4, stream>>>(rows, bucketCnt, E, nbuk);
    scan_buckets_kernel<<<1, 256, 0, stream>>>(bucketCnt, bOffs, gcursor, nbuk);
    binned_scatter_kernel<<<128, 1024, nbuk * 8, stream>>>(rows, cols, gcursor, recbuf, E, nbuk);
    bucket_sort_kernel<<<nbuk, 256, 0, stream>>>(recbuf, bOffs, clist, offs, n, nbuk);

    int nhalf = n / 2;
    agg_kernel<<<(nhalf + 3) / 4, 256, 0, stream>>>(xh, offs, clist, eps, h0h, 0, nhalf);
    agg_kernel<<<(n - nhalf + 3) / 4, 256, 0, stream>>>(xh, offs, clist, eps, h0h, nhalf, n);

    gemm1_mfma_kernel<<<ntiles, 256, 0, stream>>>(h0h, w1h, b1, h1h, partials, n);
    bn_reduce_kernel<<<16, 256, 0, stream>>>(partials, stats, ntiles);
    gemm2_mfma_kernel<<<ntiles, 256, 0, stream>>>(h1h, w2h, b2, stats, gamma, beta, out, n);
}